// Round 1
// baseline (188.912 us; speedup 1.0000x reference)
//
#include <hip/hip_runtime.h>

// Problem constants (from reference)
#define ZD_ 64
#define PD_ 16
#define DH_ 128
#define NW2 36864          // OB*IB*K = 64*64*9
#define HK_ 64             // H*KB = 8*8

// ---------------------------------------------------------------------------
// K0: hid[64][128] = relu([z_all | pde] @ W1^T + b1)
// ---------------------------------------------------------------------------
__global__ void hid_kernel(const float* __restrict__ z_all,
                           const float* __restrict__ W1,
                           const float* __restrict__ b1,
                           const float* __restrict__ pde,
                           float* __restrict__ hid) {
    int gid = blockIdx.x * 256 + threadIdx.x;   // 8192 outputs
    int r = gid >> 7;                            // z row (0..63)
    int d = gid & 127;                           // hidden unit
    const float* w = W1 + d * (ZD_ + PD_);
    const float* z = z_all + r * ZD_;
    float acc = b1[d];
    #pragma unroll 8
    for (int c = 0; c < ZD_; ++c) acc += z[c] * w[c];
    #pragma unroll
    for (int c = 0; c < PD_; ++c) acc += pde[c] * w[ZD_ + c];
    hid[gid] = fmaxf(acc, 0.0f);
}

// ---------------------------------------------------------------------------
// K1: W2T[k][n] = W2[n][k]   (so the GEMM streams W2 coalesced over n)
// 32x32 LDS tile transpose, +1 pad to kill bank conflicts.
// ---------------------------------------------------------------------------
__global__ void transpose_w2(const float* __restrict__ W2,
                             float* __restrict__ W2T) {
    __shared__ float s[32][33];
    int n0 = blockIdx.x * 32;                    // n tile (36864/32 = 1152)
    int k0 = blockIdx.y * 32;                    // k tile (128/32 = 4)
    int row = threadIdx.x >> 3;                  // 0..31
    int c4  = (threadIdx.x & 7) * 4;             // 0..28
    float4 v = *reinterpret_cast<const float4*>(W2 + (size_t)(n0 + row) * DH_ + k0 + c4);
    s[row][c4 + 0] = v.x; s[row][c4 + 1] = v.y;
    s[row][c4 + 2] = v.z; s[row][c4 + 3] = v.w;
    __syncthreads();
    float4 w;
    w.x = s[c4 + 0][row]; w.y = s[c4 + 1][row];
    w.z = s[c4 + 2][row]; w.w = s[c4 + 3][row];
    *reinterpret_cast<float4*>(W2T + (size_t)(k0 + row) * NW2 + n0 + c4) = w;
}

// ---------------------------------------------------------------------------
// K2: exe GEMM.  exe[o][i][kk] = hid[hk] . W2[n] + b2[n]
//   n = ob*576 + ib*9 + kk ; hk = h*8+kb ; o = h*64+ob ; i = kb*64+ib
// One thread computes 4 consecutive n for one hk (hk block-uniform -> the
// hid operand is a scalar broadcast; W2T loads are lane-contiguous float4).
// exe is written directly in [o][i][kk] layout: addr = o*4608 + kb*576 + (n - ob*576),
// which is consecutive in n -> coalesced float4 stores.
// ---------------------------------------------------------------------------
__global__ void exe_kernel(const float* __restrict__ hid,
                           const float* __restrict__ W2T,
                           const float* __restrict__ b2,
                           float* __restrict__ exe) {
    int hk = blockIdx.x / 36;                    // block-uniform
    int nb = blockIdx.x % 36;
    int n = (nb * 256 + threadIdx.x) * 4;        // 0..36860
    const float* hrow = hid + hk * DH_;
    float4 acc = *reinterpret_cast<const float4*>(b2 + n);
    #pragma unroll 4
    for (int k = 0; k < DH_; ++k) {
        float s = hrow[k];                       // uniform -> SGPR
        float4 w = *reinterpret_cast<const float4*>(W2T + (size_t)k * NW2 + n);
        acc.x += s * w.x; acc.y += s * w.y;
        acc.z += s * w.z; acc.w += s * w.w;
    }
    int ob = n / 576;
    int r  = n % 576;                            // = ib*9+kk, float4 stays inside one ob
    int h  = hk >> 3, kb = hk & 7;
    int o  = h * 64 + ob;
    *reinterpret_cast<float4*>(exe + (size_t)o * 4608 + kb * 576 + r) = acc;
}

// ---------------------------------------------------------------------------
// K3: outer product.  out[o][i][k][l] = exe[o][i][k] * unet[o][i][l]
// Block = (o, kb): 64 consecutive i -> exe/unet reads are 576 contiguous
// floats; out region is 5184 contiguous floats. Thread tid=(p,k) keeps its
// exe value in a register and reads the 9 unet values from LDS (broadcasty,
// conflict-free since 9 is coprime with 32). Stores: out[base + 9*tid + l].
// ---------------------------------------------------------------------------
__global__ void outer_kernel(const float* __restrict__ exe,
                             const float* __restrict__ unet,
                             float* __restrict__ out) {
    __shared__ float s_u[576];
    int b = blockIdx.x;
    int o = b >> 3, c = b & 7;
    size_t base9  = (size_t)o * 4608 + (size_t)c * 576;
    size_t base81 = (size_t)o * 41472 + (size_t)c * 5184;
    int tid = threadIdx.x;                       // 0..575 = p*9 + k
    float ev = exe[base9 + tid];
    s_u[tid] = unet[base9 + tid];
    __syncthreads();
    int p = tid / 9;
    const float* up = s_u + p * 9;
    float* op = out + base81 + (size_t)tid * 9;
    #pragma unroll
    for (int l = 0; l < 9; ++l) op[l] = ev * up[l];
}

// ---------------------------------------------------------------------------
extern "C" void kernel_launch(void* const* d_in, const int* in_sizes, int n_in,
                              void* d_out, int out_size, void* d_ws, size_t ws_size,
                              hipStream_t stream) {
    const float* z_all = (const float*)d_in[0];  // [64,64]
    const float* W1    = (const float*)d_in[1];  // [128,80]
    const float* b1    = (const float*)d_in[2];  // [128]
    const float* W2    = (const float*)d_in[3];  // [36864,128]
    const float* b2    = (const float*)d_in[4];  // [36864]
    const float* unet  = (const float*)d_in[5];  // [512,512,9]
    const float* pde   = (const float*)d_in[6];  // [16]
    float* out = (float*)d_out;                  // [512,512,9,9]

    float* ws   = (float*)d_ws;
    float* hid  = ws;                            // 8192 floats
    float* W2T  = ws + 8192;                     // 128*36864 = 4718592 floats
    float* exe  = W2T + (size_t)DH_ * NW2;       // 512*512*9 = 2359296 floats

    hid_kernel<<<32, 256, 0, stream>>>(z_all, W1, b1, pde, hid);
    transpose_w2<<<dim3(1152, 4), 256, 0, stream>>>(W2, W2T);
    exe_kernel<<<64 * 36, 256, 0, stream>>>(hid, W2T, b2, exe);
    outer_kernel<<<4096, 576, 0, stream>>>(exe, unet, out);
}

// Round 3
// 159.697 us; speedup vs baseline: 1.1829x; 1.1829x over previous
//
#include <hip/hip_runtime.h>

// Problem constants (from reference)
#define ZD_ 64
#define PD_ 16
#define DH_ 128
#define NW2 36864          // OB*IB*K = 64*64*9
#define HK_ 64             // H*KB = 8*8
#define HK_TILE 8          // hk values per exe block (register-tiled)

// ---------------------------------------------------------------------------
// K0: hid[64][128] = relu([z_all | pde] @ W1^T + b1)
// ---------------------------------------------------------------------------
__global__ void hid_kernel(const float* __restrict__ z_all,
                           const float* __restrict__ W1,
                           const float* __restrict__ b1,
                           const float* __restrict__ pde,
                           float* __restrict__ hid) {
    int gid = blockIdx.x * 256 + threadIdx.x;   // 8192 outputs
    int r = gid >> 7;                            // z row (0..63)
    int d = gid & 127;                           // hidden unit
    const float* w = W1 + d * (ZD_ + PD_);
    const float* z = z_all + r * ZD_;
    float acc = b1[d];
    #pragma unroll 8
    for (int c = 0; c < ZD_; ++c) acc += z[c] * w[c];
    #pragma unroll
    for (int c = 0; c < PD_; ++c) acc += pde[c] * w[ZD_ + c];
    hid[gid] = fmaxf(acc, 0.0f);
}

// ---------------------------------------------------------------------------
// K1: W2T[k][n] = W2[n][k]   (so the GEMM streams W2 coalesced over n)
// ---------------------------------------------------------------------------
__global__ void transpose_w2(const float* __restrict__ W2,
                             float* __restrict__ W2T) {
    __shared__ float s[32][33];
    int n0 = blockIdx.x * 32;                    // n tile (36864/32 = 1152)
    int k0 = blockIdx.y * 32;                    // k tile (128/32 = 4)
    int row = threadIdx.x >> 3;                  // 0..31
    int c4  = (threadIdx.x & 7) * 4;             // 0..28
    float4 v = *reinterpret_cast<const float4*>(W2 + (size_t)(n0 + row) * DH_ + k0 + c4);
    s[row][c4 + 0] = v.x; s[row][c4 + 1] = v.y;
    s[row][c4 + 2] = v.z; s[row][c4 + 3] = v.w;
    __syncthreads();
    float4 w;
    w.x = s[c4 + 0][row]; w.y = s[c4 + 1][row];
    w.z = s[c4 + 2][row]; w.w = s[c4 + 3][row];
    *reinterpret_cast<float4*>(W2T + (size_t)(k0 + row) * NW2 + n0 + c4) = w;
}

// ---------------------------------------------------------------------------
// K2: exe GEMM, hk-register-tiled (verified mapping from R1).
//   exe[o][i][kk] = hid[hk] . W2[n] + b2[n]
//   n = ob*576 + ib*9 + kk ; hk = h*8+kb ; o = h*64+ob ; i = kb*64+ib
// Thread = 4 consecutive n x HK_TILE(=8) hk -> 32 accumulators; each W2T
// float4 load reused 8x. hid addresses block-uniform -> scalar loads.
// ---------------------------------------------------------------------------
__global__ void exe_kernel(const float* __restrict__ hid,
                           const float* __restrict__ W2T,
                           const float* __restrict__ b2,
                           float* __restrict__ exe) {
    int nblk = blockIdx.x % 72;
    int h    = blockIdx.x / 72;                  // hk group == h (uniform)
    int n = nblk * 512 + threadIdx.x * 4;
    const float* hrow = hid + (size_t)h * HK_TILE * DH_;

    float4 bias = *reinterpret_cast<const float4*>(b2 + n);
    float4 acc[HK_TILE];
    #pragma unroll
    for (int j = 0; j < HK_TILE; ++j) acc[j] = bias;

    #pragma unroll 2
    for (int k = 0; k < DH_; k += 4) {
        float4 w0 = *reinterpret_cast<const float4*>(W2T + (size_t)(k + 0) * NW2 + n);
        float4 w1 = *reinterpret_cast<const float4*>(W2T + (size_t)(k + 1) * NW2 + n);
        float4 w2 = *reinterpret_cast<const float4*>(W2T + (size_t)(k + 2) * NW2 + n);
        float4 w3 = *reinterpret_cast<const float4*>(W2T + (size_t)(k + 3) * NW2 + n);
        #pragma unroll
        for (int j = 0; j < HK_TILE; ++j) {
            float4 hv = *reinterpret_cast<const float4*>(hrow + j * DH_ + k); // uniform -> s_load
            acc[j].x += hv.x * w0.x; acc[j].y += hv.x * w0.y;
            acc[j].z += hv.x * w0.z; acc[j].w += hv.x * w0.w;
            acc[j].x += hv.y * w1.x; acc[j].y += hv.y * w1.y;
            acc[j].z += hv.y * w1.z; acc[j].w += hv.y * w1.w;
            acc[j].x += hv.z * w2.x; acc[j].y += hv.z * w2.y;
            acc[j].z += hv.z * w2.z; acc[j].w += hv.z * w2.w;
            acc[j].x += hv.w * w3.x; acc[j].y += hv.w * w3.y;
            acc[j].z += hv.w * w3.z; acc[j].w += hv.w * w3.w;
        }
    }

    int ob = n / 576;
    int r  = n % 576;                            // 576 % 4 == 0: float4 never crosses ob
    #pragma unroll
    for (int j = 0; j < HK_TILE; ++j) {          // kb == j, h uniform
        int o = h * 64 + ob;
        *reinterpret_cast<float4*>(exe + (size_t)o * 4608 + j * 576 + r) = acc[j];
    }
}

// ---------------------------------------------------------------------------
// K3: outer product with float4 stores.
//   out[o][i][k][l] = exe[o][i][k] * unet[o][i][l]
// Block = (o, c=kb): 576 exe + 576 unet floats in LDS; output region is
// 5184 contiguous floats = 1296 float4, fully-coalesced stores.
// FIX (R2 bug): threads tid<144 load BOTH s_e[tid] and s_u[tid] — the old
// scheme needed tids up to 287 but the block only has 256 threads, leaving
// s_u[448..575] poisoned.
// ---------------------------------------------------------------------------
__global__ void outer_kernel(const float* __restrict__ exe,
                             const float* __restrict__ unet,
                             float* __restrict__ out) {
    __shared__ float s_e[576], s_u[576];
    int b = blockIdx.x;
    int o = b >> 3, c = b & 7;
    size_t base9 = (size_t)o * 4608 + (size_t)c * 576;
    const float4* e4 = reinterpret_cast<const float4*>(exe + base9);
    const float4* u4 = reinterpret_cast<const float4*>(unet + base9);
    int tid = threadIdx.x;
    if (tid < 144) {
        reinterpret_cast<float4*>(s_e)[tid] = e4[tid];
        reinterpret_cast<float4*>(s_u)[tid] = u4[tid];
    }
    __syncthreads();
    float4* o4 = reinterpret_cast<float4*>(out + (size_t)o * 41472 + (size_t)c * 5184);
    for (int idx = tid; idx < 1296; idx += 256) {
        int e0 = idx * 4;
        float4 v;
        float* vp = &v.x;
        #pragma unroll
        for (int j = 0; j < 4; ++j) {
            int e = e0 + j;
            int p = e / 81;
            int rem = e - p * 81;
            int k = rem / 9;
            int l = rem - k * 9;
            vp[j] = s_e[p * 9 + k] * s_u[p * 9 + l];
        }
        o4[idx] = v;
    }
}

// ---------------------------------------------------------------------------
extern "C" void kernel_launch(void* const* d_in, const int* in_sizes, int n_in,
                              void* d_out, int out_size, void* d_ws, size_t ws_size,
                              hipStream_t stream) {
    const float* z_all = (const float*)d_in[0];  // [64,64]
    const float* W1    = (const float*)d_in[1];  // [128,80]
    const float* b1    = (const float*)d_in[2];  // [128]
    const float* W2    = (const float*)d_in[3];  // [36864,128]
    const float* b2    = (const float*)d_in[4];  // [36864]
    const float* unet  = (const float*)d_in[5];  // [512,512,9]
    const float* pde   = (const float*)d_in[6];  // [16]
    float* out = (float*)d_out;                  // [512,512,9,9]

    float* ws   = (float*)d_ws;
    float* hid  = ws;                            // 8192 floats
    float* W2T  = ws + 8192;                     // 128*36864 = 4718592 floats
    float* exe  = W2T + (size_t)DH_ * NW2;       // 512*512*9 = 2359296 floats

    hid_kernel<<<32, 256, 0, stream>>>(z_all, W1, b1, pde, hid);
    transpose_w2<<<dim3(1152, 4), 256, 0, stream>>>(W2, W2T);
    exe_kernel<<<576, 128, 0, stream>>>(hid, W2T, b2, exe);
    outer_kernel<<<4096, 256, 0, stream>>>(exe, unet, out);
}